// Round 11
// baseline (633.399 us; speedup 1.0000x reference)
//
#include <hip/hip_runtime.h>
#include <hip/hip_bf16.h>

#define D_DIM 1024
#define VOCABSZ 32000
#define NROWSZ 4096
#define MBLK 64
#define LOG2E 1.44269504088896340736f

typedef unsigned short u16;
typedef short s8v __attribute__((ext_vector_type(8)));
typedef short s4v __attribute__((ext_vector_type(4)));
typedef float f4v __attribute__((ext_vector_type(4)));
typedef __attribute__((address_space(3))) const char* lds_p3;

static __device__ __forceinline__ u16 f2bf(float f) {
  union { float f; unsigned int u; } x; x.f = f;
  unsigned int r = x.u + 0x7fffu + ((x.u >> 16) & 1u);
  return (u16)(r >> 16);
}
static __device__ __forceinline__ unsigned int pack2(float lo, float hi) {
  return (unsigned int)f2bf(lo) | ((unsigned int)f2bf(hi) << 16);
}
static __device__ __forceinline__ unsigned int pk_rn(float lo, float hi) {
  float2 f; f.x = lo; f.y = hi;
  union { __hip_bfloat162 h; unsigned int u; } v;
  v.h = __float22bfloat162_rn(f);
  return v.u;
}
#define EXP2(x) __builtin_amdgcn_exp2f(x)

static __device__ __forceinline__ float bf2f(u16 b) {
  union { unsigned int u; float f; } x; x.u = ((unsigned int)b) << 16;
  return x.f;
}
static __device__ __forceinline__ float bfu_lo(unsigned int u) {
  union { unsigned int u; float f; } x; x.u = u << 16; return x.f;
}
static __device__ __forceinline__ float bfu_hi(unsigned int u) {
  union { unsigned int u; float f; } x; x.u = u & 0xffff0000u; return x.f;
}
static __device__ __forceinline__ f4v MFMA(s8v a, s8v b, f4v c) {
  return __builtin_amdgcn_mfma_f32_16x16x32_bf16(a, b, c, 0, 0, 0);
}

#define LGKM0_SB()                                            \
  do {                                                        \
    asm volatile("s_waitcnt lgkmcnt(0)" ::: "memory");        \
    __builtin_amdgcn_sched_barrier(0);                        \
  } while (0)

#define GLOAD_LDS16(gp, lp)                                                  \
  __builtin_amdgcn_global_load_lds(                                         \
      (const __attribute__((address_space(1))) void*)(gp),                  \
      (__attribute__((address_space(3))) void*)(lp), 16, 0, 0)

// ---------------------------------------------------------------------------
// Prep: emb fp32 -> ETt: per 32-vocab tile, a 64 KB subtiled image:
//   byte(v,d) = ((v>>2)*64 + (d>>4))*128 + (v&3)*32 + (d&15)*2
// ---------------------------------------------------------------------------
__global__ __launch_bounds__(256) void cvt3_kernel(const float* __restrict__ emb,
                                                   char* __restrict__ ETt) {
  const int b = blockIdx.x, t = threadIdx.x;
  const int v0 = b * 32;
  char* outp = ETt + ((size_t)b << 16);
#pragma unroll
  for (int k = 0; k < 16; ++k) {
    int ci = t + 256 * k;
    int v = ci >> 7;
    int d8 = ci & 127;
    const float* s = emb + (size_t)(v0 + v) * D_DIM + d8 * 8;
    float4 a = *(const float4*)s;
    float4 bb = *(const float4*)(s + 4);
    uint4 x;
    x.x = pack2(a.x, a.y); x.y = pack2(a.z, a.w);
    x.z = pack2(bb.x, bb.y); x.w = pack2(bb.z, bb.w);
    int off = ((v >> 2) * 64 + (d8 >> 1)) * 128 + (v & 3) * 32 + (d8 & 1) * 16;
    *(uint4*)(outp + off) = x;
  }
}

// ---------------------------------------------------------------------------
// Flash v11: v10 pipeline + loop-top B0 __syncthreads (drains stage DMA before
// QK reads the refilled slot — closes the ring race that NaN'd v10 and that
// v8/v9 were winning by timing luck).
// Order/tile: B0; QK(t); B1; {softmax(t) || PV2(t-1)}; B2; STAGE(t+1); PV1(t).
// 512 thr = 8 waves = 4 d-slices x 2 m-halves. KV=32 per tile.
// ---------------------------------------------------------------------------
template <int NSPLIT>
__global__ __launch_bounds__(512, 2) void flash11_kernel(
    const float* __restrict__ qg, const char* __restrict__ ETt,
    float* __restrict__ out, u16* __restrict__ pctx, float* __restrict__ pstat) {
  __shared__ char ring[2 * 65536];      // 128 KB: E-tile ring (subtiled image)
  __shared__ uint2 Sred[8 * 4 * 64];    // 16 KB: bf16x4 S^T partials
  __shared__ char Plds[2 * 4096];       // 8 KB: P double buffer
  __shared__ float lred[8][16];

  const int tid = threadIdx.x;
  const int w = tid >> 6;
  const int l = tid & 63;
  const int g = l >> 4;
  const int c = l & 15;
  const int ds = w & 3;
  const int mh = w >> 2;
  const int bid = blockIdx.x;
  const int sp = (NSPLIT == 4) ? (bid & 3) : 0;
  const int rb = (NSPLIT == 4) ? (bid >> 2) : bid;
  const int row0 = rb * MBLK;
  const int vslice = VOCABSZ / NSPLIT;
  const int ntiles = vslice / 32;
  const int gt0 = sp * ntiles;

  const f4v fzero = {0.f, 0.f, 0.f, 0.f};

  // ---- Q fragments (B-role), pre-scaled by LOG2E.
  s8v qf[2][8];
#pragma unroll
  for (int mt = 0; mt < 2; ++mt)
#pragma unroll
    for (int kt = 0; kt < 8; ++kt) {
      const float* src = qg + (size_t)(row0 + mh * 32 + 16 * mt + c) * D_DIM +
                         ds * 256 + 32 * kt + 8 * g;
      float4 a = *(const float4*)src;
      float4 b = *(const float4*)(src + 4);
      s8v v;
      v[0] = (short)f2bf(a.x * LOG2E); v[1] = (short)f2bf(a.y * LOG2E);
      v[2] = (short)f2bf(a.z * LOG2E); v[3] = (short)f2bf(a.w * LOG2E);
      v[4] = (short)f2bf(b.x * LOG2E); v[5] = (short)f2bf(b.y * LOG2E);
      v[6] = (short)f2bf(b.z * LOG2E); v[7] = (short)f2bf(b.w * LOG2E);
      qf[mt][kt] = v;
    }

  f4v acc[2][16];
#pragma unroll
  for (int mt = 0; mt < 2; ++mt)
#pragma unroll
    for (int nt = 0; nt < 16; ++nt) acc[mt][nt] = fzero;

  float lcur = 0.f;
  const int pab_s = mh * 2048 + c * 64 + g * 16;
  const int abase_s = ((2 * g) * 64 + 16 * ds) * 128 + c * 2;

#define STAGE(U)                                                             \
  {                                                                          \
    const char* _gs = ETt + (((size_t)(gt0 + (U))) << 16) + tid * 16;        \
    char* _ls = ring + (((U) & 1) << 16) + tid * 16;                         \
    _Pragma("unroll") for (int _j = 0; _j < 8; ++_j)                         \
        GLOAD_LDS16(_gs + _j * 8192, _ls + _j * 8192);                       \
  }

#define TR4(arr, NTB, ABASE)                                                 \
  _Pragma("unroll") for (int _k = 0; _k < 4; ++_k) {                         \
    const char* _a0 = (ABASE) + ((NTB) + _k) * 128;                          \
    asm volatile("ds_read_b64_tr_b16 %0, %1"                                 \
                 : "=v"(arr[2 * _k]) : "v"((lds_p3)_a0));                    \
    asm volatile("ds_read_b64_tr_b16 %0, %1"                                 \
                 : "=v"(arr[2 * _k + 1]) : "v"((lds_p3)(_a0 + 8192)));       \
  }

#define MF4(arr, NTB, PA0, PA1)                                              \
  _Pragma("unroll") for (int _k = 0; _k < 4; ++_k) {                         \
    union { s4v s[2]; s8v v; } _ev;                                          \
    _ev.s[0] = arr[2 * _k]; _ev.s[1] = arr[2 * _k + 1];                      \
    acc[0][(NTB) + _k] = MFMA((PA0), _ev.v, acc[0][(NTB) + _k]);             \
    acc[1][(NTB) + _k] = MFMA((PA1), _ev.v, acc[1][(NTB) + _k]);             \
  }

  // prologue: tile 0 staged; loop-top B0 drains it.
  STAGE(0);

  for (int t = 0; t < ntiles; ++t) {
    const char* buf = ring + ((t & 1) << 16);

    __syncthreads();                   // B0: stage(t) DMA drained (vmcnt0) for
                                       // ALL waves before any QK read of buf.

    // ================= QK: S^T partial over this wave's 256-d slice =========
#pragma unroll
    for (int vt = 0; vt < 2; ++vt) {
      const char* bp = buf + (((4 * vt + (c >> 2)) * 64 + 16 * ds + (g >> 1)) * 128 +
                              (c & 3) * 32 + (g & 1) * 16);
      f4v st0 = fzero, st1 = fzero;
#pragma unroll
      for (int kt = 0; kt < 8; ++kt) {
        s8v ek = *(const s8v*)(bp + kt * 256);
        st0 = MFMA(ek, qf[0][kt], st0);
        st1 = MFMA(ek, qf[1][kt], st1);
      }
      int qb = ((mh * 4 + vt * 2) * 4 + ds) * 64 + l;
      uint2 pk;
      pk.x = pk_rn(st0[0], st0[1]); pk.y = pk_rn(st0[2], st0[3]);
      Sred[qb] = pk;
      pk.x = pk_rn(st1[0], st1[1]); pk.y = pk_rn(st1[2], st1[3]);
      Sred[qb + 256] = pk;
    }
    __syncthreads();                   // B1: Sred visible

    // ============ window: softmax(t) interleaved with PV2(t-1) ==============
    {
      const int qq = mh * 4 + ds;
      if (t > 0) {
        const char* bufp = ring + (((t - 1) & 1) << 16);
        const char* abp = bufp + abase_s;
        const char* Pp = Plds + (((t - 1) & 1) << 12);
        s8v p0p = *(const s8v*)(Pp + pab_s);
        s8v p1p = *(const s8v*)(Pp + pab_s + 1024);
        s4v tv[8];
        // chunk 1: issue tr, do softmax sums under the latency, then MFMA
        TR4(tv, 8, abp);
        f4v ss = fzero;
#pragma unroll
        for (int ww = 0; ww < 4; ++ww) {
          uint2 u = Sred[(qq * 4 + ww) * 64 + l];
          ss[0] += bfu_lo(u.x); ss[1] += bfu_hi(u.x);
          ss[2] += bfu_lo(u.y); ss[3] += bfu_hi(u.y);
        }
        LGKM0_SB();
        __builtin_amdgcn_s_setprio(1);
        MF4(tv, 8, p0p, p1p);
        __builtin_amdgcn_s_setprio(0);
        // chunk 2: issue tr, finish softmax (exp/pack/store/lcur), then MFMA
        TR4(tv, 12, abp);
        {
          float p0 = EXP2(ss[0]), p1 = EXP2(ss[1]);
          float p2 = EXP2(ss[2]), p3 = EXP2(ss[3]);
          int pb = ((t & 1) << 12) + mh * 2048 +
                   (16 * (ds & 1) + c) * 64 + (16 * (ds >> 1) + 4 * g) * 2;
          uint2 pw; pw.x = pk_rn(p0, p1); pw.y = pk_rn(p2, p3);
          *(uint2*)(Plds + pb) = pw;
          lcur += (p0 + p1) + (p2 + p3);
        }
        LGKM0_SB();
        __builtin_amdgcn_s_setprio(1);
        MF4(tv, 12, p0p, p1p);
        __builtin_amdgcn_s_setprio(0);
      } else {
        f4v ss = fzero;
#pragma unroll
        for (int ww = 0; ww < 4; ++ww) {
          uint2 u = Sred[(qq * 4 + ww) * 64 + l];
          ss[0] += bfu_lo(u.x); ss[1] += bfu_hi(u.x);
          ss[2] += bfu_lo(u.y); ss[3] += bfu_hi(u.y);
        }
        float p0 = EXP2(ss[0]), p1 = EXP2(ss[1]);
        float p2 = EXP2(ss[2]), p3 = EXP2(ss[3]);
        int pb = ((t & 1) << 12) + mh * 2048 +
                 (16 * (ds & 1) + c) * 64 + (16 * (ds >> 1) + 4 * g) * 2;
        uint2 pw; pw.x = pk_rn(p0, p1); pw.y = pk_rn(p2, p3);
        *(uint2*)(Plds + pb) = pw;
        lcur += (p0 + p1) + (p2 + p3);
      }
    }
    __syncthreads();                   // B2: P(t) visible; PV2(t-1) done

    // stage next tile: in flight across PV1(t), drained at B0(t+1)
    if (t + 1 < ntiles) STAGE(t + 1);

    // ================= PV1(t): nt 0..7 ======================================
    {
      const char* Pc = Plds + ((t & 1) << 12);
      s8v p0 = *(const s8v*)(Pc + pab_s);
      s8v p1 = *(const s8v*)(Pc + pab_s + 1024);
      const char* ab = buf + abase_s;
      s4v tv[8];
      TR4(tv, 0, ab);
      LGKM0_SB();
      MF4(tv, 0, p0, p1);
      TR4(tv, 4, ab);
      LGKM0_SB();
      MF4(tv, 4, p0, p1);
    }
  }
  // ---- epilogue: PV2 of the last tile (P and ring slot still valid)
  {
    const int tl = ntiles - 1;
    const char* bufp = ring + ((tl & 1) << 16);
    const char* abp = bufp + abase_s;
    const char* Pp = Plds + ((tl & 1) << 12);
    s8v p0p = *(const s8v*)(Pp + pab_s);
    s8v p1p = *(const s8v*)(Pp + pab_s + 1024);
    s4v tv[8];
    TR4(tv, 8, abp);
    LGKM0_SB();
    MF4(tv, 8, p0p, p1p);
    TR4(tv, 12, abp);
    LGKM0_SB();
    MF4(tv, 12, p0p, p1p);
  }
#undef STAGE
#undef TR4
#undef MF4

  // ---- finalize: deferred row-sum reduction, then normalize+write
  {
    float lp = lcur;
    lp += __shfl_xor(lp, 16);
    lp += __shfl_xor(lp, 32);
    __syncthreads();
    if (g == 0) lred[mh * 4 + ds][c] = lp;
  }
  __syncthreads();

  if (NSPLIT == 1) {
#pragma unroll
    for (int mt = 0; mt < 2; ++mt) {
      float inv[4];
#pragma unroll
      for (int r = 0; r < 4; ++r)
        inv[r] = 1.f / (lred[mh * 4 + mt][4 * g + r] + lred[mh * 4 + 2 + mt][4 * g + r]);
#pragma unroll
      for (int nt = 0; nt < 16; ++nt)
#pragma unroll
        for (int r = 0; r < 4; ++r) {
          size_t o = (size_t)(row0 + mh * 32 + 16 * mt + 4 * g + r) * D_DIM +
                     ds * 256 + 16 * nt + c;
          out[o] = acc[mt][nt][r] * inv[r] + qg[o];
        }
    }
  } else {
    u16* pc = pctx + (size_t)sp * NROWSZ * D_DIM;
#pragma unroll
    for (int mt = 0; mt < 2; ++mt)
#pragma unroll
      for (int nt = 0; nt < 16; ++nt)
#pragma unroll
        for (int r = 0; r < 4; ++r)
          pc[(size_t)(row0 + mh * 32 + 16 * mt + 4 * g + r) * D_DIM +
             ds * 256 + 16 * nt + c] = f2bf(acc[mt][nt][r]);
    if (ds < 2 && g == 0)
      pstat[(size_t)sp * NROWSZ + row0 + mh * 32 + 16 * ds + c] =
          lred[mh * 4 + ds][c] + lred[mh * 4 + 2 + ds][c];
  }
}

// ---------------------------------------------------------------------------
// Combine NSPLIT=4 partials: out = (sum ctx_sp) / (sum l_sp) + q
// ---------------------------------------------------------------------------
__global__ __launch_bounds__(256) void combine2_kernel(const float* __restrict__ qg,
                                                       const u16* __restrict__ pctx,
                                                       const float* __restrict__ pstat,
                                                       float* __restrict__ out) {
  const int r = blockIdx.x;
  const int t = threadIdx.x;
  float L = pstat[r] + pstat[NROWSZ + r] + pstat[2 * NROWSZ + r] + pstat[3 * NROWSZ + r];
  float inv = 1.f / L;
  size_t o = (size_t)r * D_DIM + t * 4;
  float sx = 0.f, sy = 0.f, sz = 0.f, sw = 0.f;
#pragma unroll
  for (int sp = 0; sp < 4; ++sp) {
    ushort4 u = *(const ushort4*)(pctx + (size_t)sp * NROWSZ * D_DIM + o);
    sx += bf2f(u.x); sy += bf2f(u.y); sz += bf2f(u.z); sw += bf2f(u.w);
  }
  float4 qv = *(const float4*)(qg + o);
  float4 res;
  res.x = sx * inv + qv.x;
  res.y = sy * inv + qv.y;
  res.z = sz * inv + qv.z;
  res.w = sw * inv + qv.w;
  *(float4*)(out + o) = res;
}

// ---------------------------------------------------------------------------
// Naive correctness fallback (tiny ws): one q-row per block.
// ---------------------------------------------------------------------------
__global__ __launch_bounds__(256) void naive_kernel(const float* __restrict__ qg,
                                                    const float* __restrict__ emb,
                                                    float* __restrict__ out) {
  __shared__ float s[VOCABSZ];
  __shared__ float qrow[D_DIM];
  __shared__ float lsh[4];
  const int r = blockIdx.x;
  const int t = threadIdx.x;
  for (int i = t; i < D_DIM; i += 256) qrow[i] = qg[(size_t)r * D_DIM + i];
  __syncthreads();
  float lpart = 0.f;
  for (int v = t; v < VOCABSZ; v += 256) {
    float dot = 0.f;
    for (int d = 0; d < D_DIM; d += 4) {
      float4 e = *(const float4*)(emb + (size_t)v * D_DIM + d);
      dot += qrow[d] * e.x + qrow[d + 1] * e.y + qrow[d + 2] * e.z + qrow[d + 3] * e.w;
    }
    float p = exp2f(dot * LOG2E);
    s[v] = p;
    lpart += p;
  }
  for (int o = 32; o; o >>= 1) lpart += __shfl_xor(lpart, o);
  if ((t & 63) == 0) lsh[t >> 6] = lpart;
  __syncthreads();
  float inv = 1.f / (lsh[0] + lsh[1] + lsh[2] + lsh[3]);
  float ax = 0.f, ay = 0.f, az = 0.f, aw = 0.f;
  for (int v = 0; v < VOCABSZ; ++v) {
    float p = s[v];
    float4 e = *(const float4*)(emb + (size_t)v * D_DIM + t * 4);
    ax += p * e.x; ay += p * e.y; az += p * e.z; aw += p * e.w;
  }
  size_t o = (size_t)r * D_DIM + t * 4;
  float4 qv = *(const float4*)(qg + o);
  float4 res;
  res.x = ax * inv + qv.x;
  res.y = ay * inv + qv.y;
  res.z = az * inv + qv.z;
  res.w = aw * inv + qv.w;
  *(float4*)(out + o) = res;
}

extern "C" void kernel_launch(void* const* d_in, const int* in_sizes, int n_in,
                              void* d_out, int out_size, void* d_ws, size_t ws_size,
                              hipStream_t stream) {
  const float* q = (const float*)d_in[0];
  const float* emb = (const float*)d_in[1];
  float* out = (float*)d_out;
  char* ws = (char*)d_ws;

  const size_t ETT_BYTES = 65536000ull;                      // 1000 tiles x 64 KB
  const size_t PCTX_BYTES = 4ull * NROWSZ * D_DIM * 2;       // 33,554,432
  const size_t PSTAT_BYTES = 4ull * NROWSZ * 4;              // 65,536

  if (ws_size >= ETT_BYTES + PCTX_BYTES + PSTAT_BYTES) {     // 99,155,968
    char* ETt = ws;
    u16* pctx = (u16*)(ws + ETT_BYTES);
    float* pstat = (float*)(ws + ETT_BYTES + PCTX_BYTES);
    cvt3_kernel<<<VOCABSZ / 32, 256, 0, stream>>>(emb, ETt);
    flash11_kernel<4><<<256, 512, 0, stream>>>(q, ETt, out, pctx, pstat);
    combine2_kernel<<<NROWSZ, 256, 0, stream>>>(q, pctx, pstat, out);
  } else if (ws_size >= ETT_BYTES) {
    char* ETt = ws;
    cvt3_kernel<<<VOCABSZ / 32, 256, 0, stream>>>(emb, ETt);
    flash11_kernel<1><<<NROWSZ / MBLK, 512, 0, stream>>>(q, ETt, out, nullptr, nullptr);
  } else {
    naive_kernel<<<NROWSZ, 256, 0, stream>>>(q, emb, out);
  }
}

// Round 12
// 607.172 us; speedup vs baseline: 1.0432x; 1.0432x over previous
//
#include <hip/hip_runtime.h>
#include <hip/hip_bf16.h>

#define D_DIM 1024
#define VOCABSZ 32000
#define NROWSZ 4096
#define MBLK 64
#define LOG2E 1.44269504088896340736f

typedef unsigned short u16;
typedef short s8v __attribute__((ext_vector_type(8)));
typedef short s4v __attribute__((ext_vector_type(4)));
typedef float f4v __attribute__((ext_vector_type(4)));
typedef __attribute__((address_space(3))) const char* lds_p3;

static __device__ __forceinline__ u16 f2bf(float f) {
  union { float f; unsigned int u; } x; x.f = f;
  unsigned int r = x.u + 0x7fffu + ((x.u >> 16) & 1u);
  return (u16)(r >> 16);
}
static __device__ __forceinline__ unsigned int pack2(float lo, float hi) {
  return (unsigned int)f2bf(lo) | ((unsigned int)f2bf(hi) << 16);
}
static __device__ __forceinline__ unsigned int pk_rn(float lo, float hi) {
  float2 f; f.x = lo; f.y = hi;
  union { __hip_bfloat162 h; unsigned int u; } v;
  v.h = __float22bfloat162_rn(f);
  return v.u;
}
#define EXP2(x) __builtin_amdgcn_exp2f(x)

static __device__ __forceinline__ float bf2f(u16 b) {
  union { unsigned int u; float f; } x; x.u = ((unsigned int)b) << 16;
  return x.f;
}
static __device__ __forceinline__ float bfu_lo(unsigned int u) {
  union { unsigned int u; float f; } x; x.u = u << 16; return x.f;
}
static __device__ __forceinline__ float bfu_hi(unsigned int u) {
  union { unsigned int u; float f; } x; x.u = u & 0xffff0000u; return x.f;
}
static __device__ __forceinline__ f4v MFMA(s8v a, s8v b, f4v c) {
  return __builtin_amdgcn_mfma_f32_16x16x32_bf16(a, b, c, 0, 0, 0);
}

#define GLOAD_LDS16(gp, lp)                                                  \
  __builtin_amdgcn_global_load_lds(                                         \
      (const __attribute__((address_space(1))) void*)(gp),                  \
      (__attribute__((address_space(3))) void*)(lp), 16, 0, 0)

// ---------------------------------------------------------------------------
// Prep: emb fp32 -> ETt: per 32-vocab tile, a 64 KB subtiled image:
//   byte(v,d) = ((v>>2)*64 + (d>>4))*128 + (v&3)*32 + (d&15)*2
// QK A-frags = contiguous 16B rows; PV B-frags via ds_read_b64_tr_b16.
// ---------------------------------------------------------------------------
__global__ __launch_bounds__(256) void cvt3_kernel(const float* __restrict__ emb,
                                                   char* __restrict__ ETt) {
  const int b = blockIdx.x, t = threadIdx.x;
  const int v0 = b * 32;
  char* outp = ETt + ((size_t)b << 16);
#pragma unroll
  for (int k = 0; k < 16; ++k) {
    int ci = t + 256 * k;       // 0..4095
    int v = ci >> 7;            // 0..31
    int d8 = ci & 127;          // d = 8*d8
    const float* s = emb + (size_t)(v0 + v) * D_DIM + d8 * 8;
    float4 a = *(const float4*)s;
    float4 bb = *(const float4*)(s + 4);
    uint4 x;
    x.x = pack2(a.x, a.y); x.y = pack2(a.z, a.w);
    x.z = pack2(bb.x, bb.y); x.w = pack2(bb.z, bb.w);
    int off = ((v >> 2) * 64 + (d8 >> 1)) * 128 + (v & 3) * 32 + (d8 & 1) * 16;
    *(uint4*)(outp + off) = x;
  }
}

// ---------------------------------------------------------------------------
// Flash v12: EXACT v9 schedule (proven 591us) + two register-level deltas:
//  (1) QK accumulation split into two 4-deep MFMA chains per st (4 chains/wave
//      instead of 2 -> better matrix-pipe fill during QK).
//  (2) PV tr-read asm outputs written directly into union halves (gives the
//      allocator the s4v-pair constraint; removes potential v_mov copies).
// 512 thr = 8 waves = 4 d-slices x 2 m-halves. KV=32 per tile.
// ---------------------------------------------------------------------------
template <int NSPLIT>
__global__ __launch_bounds__(512, 2) void flash12_kernel(
    const float* __restrict__ qg, const char* __restrict__ ETt,
    float* __restrict__ out, u16* __restrict__ pctx, float* __restrict__ pstat) {
  __shared__ char ring[2 * 65536];      // 128 KB: E-tile ring (subtiled image)
  __shared__ uint2 Sred[8 * 4 * 64];    // 16 KB: bf16x4 S^T partials
  __shared__ char Plds[4096];           // 4 KB: P [mh][32 m][32 v] bf16
  __shared__ float lred[8][16];

  const int tid = threadIdx.x;
  const int w = tid >> 6;
  const int l = tid & 63;
  const int g = l >> 4;
  const int c = l & 15;
  const int ds = w & 3;                 // d-slice: [ds*256, ds*256+256)
  const int mh = w >> 2;                // m-half: rows [mh*32, mh*32+32)
  const int bid = blockIdx.x;
  const int sp = (NSPLIT == 4) ? (bid & 3) : 0;
  const int rb = (NSPLIT == 4) ? (bid >> 2) : bid;
  const int row0 = rb * MBLK;
  const int vslice = VOCABSZ / NSPLIT;
  const int ntiles = vslice / 32;       // 250 or 1000
  const int gt0 = sp * ntiles;

  const f4v fzero = {0.f, 0.f, 0.f, 0.f};

  // ---- Q fragments (B-role), pre-scaled by LOG2E so softmax is exp2-direct.
  s8v qf[2][8];
#pragma unroll
  for (int mt = 0; mt < 2; ++mt)
#pragma unroll
    for (int kt = 0; kt < 8; ++kt) {
      const float* src = qg + (size_t)(row0 + mh * 32 + 16 * mt + c) * D_DIM +
                         ds * 256 + 32 * kt + 8 * g;
      float4 a = *(const float4*)src;
      float4 b = *(const float4*)(src + 4);
      s8v v;
      v[0] = (short)f2bf(a.x * LOG2E); v[1] = (short)f2bf(a.y * LOG2E);
      v[2] = (short)f2bf(a.z * LOG2E); v[3] = (short)f2bf(a.w * LOG2E);
      v[4] = (short)f2bf(b.x * LOG2E); v[5] = (short)f2bf(b.y * LOG2E);
      v[6] = (short)f2bf(b.z * LOG2E); v[7] = (short)f2bf(b.w * LOG2E);
      qf[mt][kt] = v;
    }

  f4v acc[2][16];
#pragma unroll
  for (int mt = 0; mt < 2; ++mt)
#pragma unroll
    for (int nt = 0; nt < 16; ++nt) acc[mt][nt] = fzero;

  float lcur = 0.f;

#define STAGE(U)                                                             \
  {                                                                          \
    const char* _gs = ETt + (((size_t)(gt0 + (U))) << 16) + tid * 16;        \
    char* _ls = ring + (((U) & 1) << 16) + tid * 16;                         \
    _Pragma("unroll") for (int _j = 0; _j < 8; ++_j)                         \
        GLOAD_LDS16(_gs + _j * 8192, _ls + _j * 8192);                       \
  }

  // prologue: tile 0 staged and drained (syncthreads emits vmcnt(0))
  STAGE(0);
  __syncthreads();

  for (int t = 0; t < ntiles; ++t) {
    const char* buf = ring + ((t & 1) << 16);

    // ================= QK: S^T partial over this wave's 256-d slice =========
    // Two 4-deep MFMA chains per output (4 independent chains total).
#pragma unroll
    for (int vt = 0; vt < 2; ++vt) {
      const char* bp = buf + (((4 * vt + (c >> 2)) * 64 + 16 * ds + (g >> 1)) * 128 +
                              (c & 3) * 32 + (g & 1) * 16);
      f4v st0a = fzero, st0b = fzero, st1a = fzero, st1b = fzero;
#pragma unroll
      for (int kt = 0; kt < 4; ++kt) {
        s8v ek = *(const s8v*)(bp + kt * 256);
        st0a = MFMA(ek, qf[0][kt], st0a);
        st1a = MFMA(ek, qf[1][kt], st1a);
      }
#pragma unroll
      for (int kt = 4; kt < 8; ++kt) {
        s8v ek = *(const s8v*)(bp + kt * 256);
        st0b = MFMA(ek, qf[0][kt], st0b);
        st1b = MFMA(ek, qf[1][kt], st1b);
      }
      f4v st0 = st0a + st0b;
      f4v st1 = st1a + st1b;
      int qb = ((mh * 4 + vt * 2) * 4 + ds) * 64 + l;
      uint2 pk;
      pk.x = pk_rn(st0[0], st0[1]); pk.y = pk_rn(st0[2], st0[3]);
      Sred[qb] = pk;
      pk.x = pk_rn(st1[0], st1[1]); pk.y = pk_rn(st1[2], st1[3]);
      Sred[qb + 256] = pk;             // mt=1 -> quadrant q+1
    }
    __syncthreads();                   // B1: Sred visible; drains prior STAGE DMA
                                       // (issued a full PV-phase ago -> hidden)

    // ================= softmax: wave (ds,mh) owns quadrant =================
    {
      int qq = mh * 4 + ds;
      f4v ss = fzero;
#pragma unroll
      for (int ww = 0; ww < 4; ++ww) {
        uint2 u = Sred[(qq * 4 + ww) * 64 + l];
        ss[0] += bfu_lo(u.x); ss[1] += bfu_hi(u.x);
        ss[2] += bfu_lo(u.y); ss[3] += bfu_hi(u.y);
      }
      float p0 = EXP2(ss[0]), p1 = EXP2(ss[1]);
      float p2 = EXP2(ss[2]), p3 = EXP2(ss[3]);
      int pb = mh * 2048 + (16 * (ds & 1) + c) * 64 + (16 * (ds >> 1) + 4 * g) * 2;
      uint2 pw; pw.x = pk_rn(p0, p1); pw.y = pk_rn(p2, p3);
      *(uint2*)(Plds + pb) = pw;
      lcur += (p0 + p1) + (p2 + p3);   // row-sum shfl deferred to epilogue
    }
    __syncthreads();                   // B2: P visible (no DMA in flight here)

    // stage next tile: in flight across PV + next QK, drained at next B1
    if (t + 1 < ntiles) STAGE(t + 1);

    // ================= PV: A = P rows (b128), B = E^T via tr-reads ==========
    {
      int pab = mh * 2048 + c * 64 + g * 16;
      s8v pa0 = *(const s8v*)(Plds + pab);
      s8v pa1 = *(const s8v*)(Plds + pab + 1024);
#pragma unroll
      for (int bb = 0; bb < 2; ++bb) {
        union { s4v s[2]; s8v v; } ev[8];
#pragma unroll
        for (int k = 0; k < 8; ++k) {
          int nt = bb * 8 + k;
          const char* a0 = buf + ((2 * g) * 64 + 16 * ds + nt) * 128 + c * 2;
          asm volatile("ds_read_b64_tr_b16 %0, %1"
                       : "=v"(ev[k].s[0]) : "v"((lds_p3)a0));
          asm volatile("ds_read_b64_tr_b16 %0, %1"
                       : "=v"(ev[k].s[1]) : "v"((lds_p3)(a0 + 8192)));
        }
        asm volatile("s_waitcnt lgkmcnt(0)" ::: "memory");
        __builtin_amdgcn_sched_barrier(0);
#pragma unroll
        for (int k = 0; k < 8; ++k) {
          int nt = bb * 8 + k;
          acc[0][nt] = MFMA(pa0, ev[k].v, acc[0][nt]);
          acc[1][nt] = MFMA(pa1, ev[k].v, acc[1][nt]);
        }
      }
    }
  }
#undef STAGE

  // ---- finalize: deferred row-sum reduction, then normalize+write
  {
    float lp = lcur;
    lp += __shfl_xor(lp, 16);
    lp += __shfl_xor(lp, 32);
    __syncthreads();
    if (g == 0) lred[mh * 4 + ds][c] = lp;
  }
  __syncthreads();

  if (NSPLIT == 1) {
#pragma unroll
    for (int mt = 0; mt < 2; ++mt) {
      float inv[4];
#pragma unroll
      for (int r = 0; r < 4; ++r)
        inv[r] = 1.f / (lred[mh * 4 + mt][4 * g + r] + lred[mh * 4 + 2 + mt][4 * g + r]);
#pragma unroll
      for (int nt = 0; nt < 16; ++nt)
#pragma unroll
        for (int r = 0; r < 4; ++r) {
          size_t o = (size_t)(row0 + mh * 32 + 16 * mt + 4 * g + r) * D_DIM +
                     ds * 256 + 16 * nt + c;
          out[o] = acc[mt][nt][r] * inv[r] + qg[o];
        }
    }
  } else {
    u16* pc = pctx + (size_t)sp * NROWSZ * D_DIM;
#pragma unroll
    for (int mt = 0; mt < 2; ++mt)
#pragma unroll
      for (int nt = 0; nt < 16; ++nt)
#pragma unroll
        for (int r = 0; r < 4; ++r)
          pc[(size_t)(row0 + mh * 32 + 16 * mt + 4 * g + r) * D_DIM +
             ds * 256 + 16 * nt + c] = f2bf(acc[mt][nt][r]);
    if (ds < 2 && g == 0)
      pstat[(size_t)sp * NROWSZ + row0 + mh * 32 + 16 * ds + c] =
          lred[mh * 4 + ds][c] + lred[mh * 4 + 2 + ds][c];
  }
}

// ---------------------------------------------------------------------------
// Combine NSPLIT=4 partials: out = (sum ctx_sp) / (sum l_sp) + q
// ---------------------------------------------------------------------------
__global__ __launch_bounds__(256) void combine2_kernel(const float* __restrict__ qg,
                                                       const u16* __restrict__ pctx,
                                                       const float* __restrict__ pstat,
                                                       float* __restrict__ out) {
  const int r = blockIdx.x;
  const int t = threadIdx.x;
  float L = pstat[r] + pstat[NROWSZ + r] + pstat[2 * NROWSZ + r] + pstat[3 * NROWSZ + r];
  float inv = 1.f / L;
  size_t o = (size_t)r * D_DIM + t * 4;
  float sx = 0.f, sy = 0.f, sz = 0.f, sw = 0.f;
#pragma unroll
  for (int sp = 0; sp < 4; ++sp) {
    ushort4 u = *(const ushort4*)(pctx + (size_t)sp * NROWSZ * D_DIM + o);
    sx += bf2f(u.x); sy += bf2f(u.y); sz += bf2f(u.z); sw += bf2f(u.w);
  }
  float4 qv = *(const float4*)(qg + o);
  float4 res;
  res.x = sx * inv + qv.x;
  res.y = sy * inv + qv.y;
  res.z = sz * inv + qv.z;
  res.w = sw * inv + qv.w;
  *(float4*)(out + o) = res;
}

// ---------------------------------------------------------------------------
// Naive correctness fallback (tiny ws): one q-row per block.
// ---------------------------------------------------------------------------
__global__ __launch_bounds__(256) void naive_kernel(const float* __restrict__ qg,
                                                    const float* __restrict__ emb,
                                                    float* __restrict__ out) {
  __shared__ float s[VOCABSZ];
  __shared__ float qrow[D_DIM];
  __shared__ float lsh[4];
  const int r = blockIdx.x;
  const int t = threadIdx.x;
  for (int i = t; i < D_DIM; i += 256) qrow[i] = qg[(size_t)r * D_DIM + i];
  __syncthreads();
  float lpart = 0.f;
  for (int v = t; v < VOCABSZ; v += 256) {
    float dot = 0.f;
    for (int d = 0; d < D_DIM; d += 4) {
      float4 e = *(const float4*)(emb + (size_t)v * D_DIM + d);
      dot += qrow[d] * e.x + qrow[d + 1] * e.y + qrow[d + 2] * e.z + qrow[d + 3] * e.w;
    }
    float p = exp2f(dot * LOG2E);
    s[v] = p;
    lpart += p;
  }
  for (int o = 32; o; o >>= 1) lpart += __shfl_xor(lpart, o);
  if ((t & 63) == 0) lsh[t >> 6] = lpart;
  __syncthreads();
  float inv = 1.f / (lsh[0] + lsh[1] + lsh[2] + lsh[3]);
  float ax = 0.f, ay = 0.f, az = 0.f, aw = 0.f;
  for (int v = 0; v < VOCABSZ; ++v) {
    float p = s[v];
    float4 e = *(const float4*)(emb + (size_t)v * D_DIM + t * 4);
    ax += p * e.x; ay += p * e.y; az += p * e.z; aw += p * e.w;
  }
  size_t o = (size_t)r * D_DIM + t * 4;
  float4 qv = *(const float4*)(qg + o);
  float4 res;
  res.x = ax * inv + qv.x;
  res.y = ay * inv + qv.y;
  res.z = az * inv + qv.z;
  res.w = aw * inv + qv.w;
  *(float4*)(out + o) = res;
}

extern "C" void kernel_launch(void* const* d_in, const int* in_sizes, int n_in,
                              void* d_out, int out_size, void* d_ws, size_t ws_size,
                              hipStream_t stream) {
  const float* q = (const float*)d_in[0];
  const float* emb = (const float*)d_in[1];
  float* out = (float*)d_out;
  char* ws = (char*)d_ws;

  const size_t ETT_BYTES = 65536000ull;                      // 1000 tiles x 64 KB
  const size_t PCTX_BYTES = 4ull * NROWSZ * D_DIM * 2;       // 33,554,432
  const size_t PSTAT_BYTES = 4ull * NROWSZ * 4;              // 65,536

  if (ws_size >= ETT_BYTES + PCTX_BYTES + PSTAT_BYTES) {     // 99,155,968
    char* ETt = ws;
    u16* pctx = (u16*)(ws + ETT_BYTES);
    float* pstat = (float*)(ws + ETT_BYTES + PCTX_BYTES);
    cvt3_kernel<<<VOCABSZ / 32, 256, 0, stream>>>(emb, ETt);
    flash12_kernel<4><<<256, 512, 0, stream>>>(q, ETt, out, pctx, pstat);
    combine2_kernel<<<NROWSZ, 256, 0, stream>>>(q, pctx, pstat, out);
  } else if (ws_size >= ETT_BYTES) {
    char* ETt = ws;
    cvt3_kernel<<<VOCABSZ / 32, 256, 0, stream>>>(emb, ETt);
    flash12_kernel<1><<<NROWSZ / MBLK, 512, 0, stream>>>(q, ETt, out, nullptr, nullptr);
  } else {
    naive_kernel<<<NROWSZ, 256, 0, stream>>>(q, emb, out);
  }
}

// Round 13
// 590.638 us; speedup vs baseline: 1.0724x; 1.0280x over previous
//
#include <hip/hip_runtime.h>
#include <hip/hip_bf16.h>

#define D_DIM 1024
#define VOCABSZ 32000
#define NROWSZ 4096
#define MBLK 64
#define LOG2E 1.44269504088896340736f

typedef unsigned short u16;
typedef short s8v __attribute__((ext_vector_type(8)));
typedef short s4v __attribute__((ext_vector_type(4)));
typedef float f4v __attribute__((ext_vector_type(4)));
typedef __attribute__((address_space(3))) const char* lds_p3;

static __device__ __forceinline__ u16 f2bf(float f) {
  union { float f; unsigned int u; } x; x.f = f;
  unsigned int r = x.u + 0x7fffu + ((x.u >> 16) & 1u);
  return (u16)(r >> 16);
}
static __device__ __forceinline__ unsigned int pack2(float lo, float hi) {
  return (unsigned int)f2bf(lo) | ((unsigned int)f2bf(hi) << 16);
}
static __device__ __forceinline__ unsigned int pk_rn(float lo, float hi) {
  float2 f; f.x = lo; f.y = hi;
  union { __hip_bfloat162 h; unsigned int u; } v;
  v.h = __float22bfloat162_rn(f);
  return v.u;
}
#define EXP2(x) __builtin_amdgcn_exp2f(x)

static __device__ __forceinline__ float bf2f(u16 b) {
  union { unsigned int u; float f; } x; x.u = ((unsigned int)b) << 16;
  return x.f;
}
static __device__ __forceinline__ float bfu_lo(unsigned int u) {
  union { unsigned int u; float f; } x; x.u = u << 16; return x.f;
}
static __device__ __forceinline__ float bfu_hi(unsigned int u) {
  union { unsigned int u; float f; } x; x.u = u & 0xffff0000u; return x.f;
}
static __device__ __forceinline__ f4v MFMA(s8v a, s8v b, f4v c) {
  return __builtin_amdgcn_mfma_f32_16x16x32_bf16(a, b, c, 0, 0, 0);
}

#define LGKM0_SB()                                            \
  do {                                                        \
    asm volatile("s_waitcnt lgkmcnt(0)" ::: "memory");        \
    __builtin_amdgcn_sched_barrier(0);                        \
  } while (0)

#define GLOAD_LDS16(gp, lp)                                                  \
  __builtin_amdgcn_global_load_lds(                                         \
      (const __attribute__((address_space(1))) void*)(gp),                  \
      (__attribute__((address_space(3))) void*)(lp), 16, 0, 0)

// ---------------------------------------------------------------------------
// Prep: emb fp32 -> ETt: per 32-vocab tile, a 64 KB subtiled image:
//   byte(v,d) = ((v>>2)*64 + (d>>4))*128 + (v&3)*32 + (d&15)*2
// QK A-frags = contiguous 16B rows; PV B-frags via ds_read_b64_tr_b16.
// ---------------------------------------------------------------------------
__global__ __launch_bounds__(256) void cvt3_kernel(const float* __restrict__ emb,
                                                   char* __restrict__ ETt) {
  const int b = blockIdx.x, t = threadIdx.x;
  const int v0 = b * 32;
  char* outp = ETt + ((size_t)b << 16);
#pragma unroll
  for (int k = 0; k < 16; ++k) {
    int ci = t + 256 * k;       // 0..4095
    int v = ci >> 7;            // 0..31
    int d8 = ci & 127;          // d = 8*d8
    const float* s = emb + (size_t)(v0 + v) * D_DIM + d8 * 8;
    float4 a = *(const float4*)s;
    float4 bb = *(const float4*)(s + 4);
    uint4 x;
    x.x = pack2(a.x, a.y); x.y = pack2(a.z, a.w);
    x.z = pack2(bb.x, bb.y); x.w = pack2(bb.z, bb.w);
    int off = ((v >> 2) * 64 + (d8 >> 1)) * 128 + (v & 3) * 32 + (d8 & 1) * 16;
    *(uint4*)(outp + off) = x;
  }
}

// ---------------------------------------------------------------------------
// Flash v13: EXACT v9 schedule (proven 591us) + rolling 4-nt PV pipeline:
// only batch 0's tr-read latency exposed; batches 1-3 hide under the previous
// batch's 8 MFMAs. Zero register delta (two 4-nt unions = one 8-nt batch).
// All waits lgkmcnt(0)+sched_barrier(0) (proven-safe discipline).
// 512 thr = 8 waves = 4 d-slices x 2 m-halves. KV=32 per tile.
// ---------------------------------------------------------------------------
template <int NSPLIT>
__global__ __launch_bounds__(512, 2) void flash13_kernel(
    const float* __restrict__ qg, const char* __restrict__ ETt,
    float* __restrict__ out, u16* __restrict__ pctx, float* __restrict__ pstat) {
  __shared__ char ring[2 * 65536];      // 128 KB: E-tile ring (subtiled image)
  __shared__ uint2 Sred[8 * 4 * 64];    // 16 KB: bf16x4 S^T partials
  __shared__ char Plds[4096];           // 4 KB: P [mh][32 m][32 v] bf16
  __shared__ float lred[8][16];

  const int tid = threadIdx.x;
  const int w = tid >> 6;
  const int l = tid & 63;
  const int g = l >> 4;
  const int c = l & 15;
  const int ds = w & 3;                 // d-slice: [ds*256, ds*256+256)
  const int mh = w >> 2;                // m-half: rows [mh*32, mh*32+32)
  const int bid = blockIdx.x;
  const int sp = (NSPLIT == 4) ? (bid & 3) : 0;
  const int rb = (NSPLIT == 4) ? (bid >> 2) : bid;
  const int row0 = rb * MBLK;
  const int vslice = VOCABSZ / NSPLIT;
  const int ntiles = vslice / 32;       // 250 or 1000
  const int gt0 = sp * ntiles;

  const f4v fzero = {0.f, 0.f, 0.f, 0.f};

  // ---- Q fragments (B-role), pre-scaled by LOG2E so softmax is exp2-direct.
  s8v qf[2][8];
#pragma unroll
  for (int mt = 0; mt < 2; ++mt)
#pragma unroll
    for (int kt = 0; kt < 8; ++kt) {
      const float* src = qg + (size_t)(row0 + mh * 32 + 16 * mt + c) * D_DIM +
                         ds * 256 + 32 * kt + 8 * g;
      float4 a = *(const float4*)src;
      float4 b = *(const float4*)(src + 4);
      s8v v;
      v[0] = (short)f2bf(a.x * LOG2E); v[1] = (short)f2bf(a.y * LOG2E);
      v[2] = (short)f2bf(a.z * LOG2E); v[3] = (short)f2bf(a.w * LOG2E);
      v[4] = (short)f2bf(b.x * LOG2E); v[5] = (short)f2bf(b.y * LOG2E);
      v[6] = (short)f2bf(b.z * LOG2E); v[7] = (short)f2bf(b.w * LOG2E);
      qf[mt][kt] = v;
    }

  f4v acc[2][16];
#pragma unroll
  for (int mt = 0; mt < 2; ++mt)
#pragma unroll
    for (int nt = 0; nt < 16; ++nt) acc[mt][nt] = fzero;

  float lcur = 0.f;

#define STAGE(U)                                                             \
  {                                                                          \
    const char* _gs = ETt + (((size_t)(gt0 + (U))) << 16) + tid * 16;        \
    char* _ls = ring + (((U) & 1) << 16) + tid * 16;                         \
    _Pragma("unroll") for (int _j = 0; _j < 8; ++_j)                         \
        GLOAD_LDS16(_gs + _j * 8192, _ls + _j * 8192);                       \
  }

#define TR4X(arr, NTB, ABASE)                                                \
  _Pragma("unroll") for (int _k = 0; _k < 4; ++_k) {                         \
    const char* _a0 = (ABASE) + ((NTB) + _k) * 128;                          \
    asm volatile("ds_read_b64_tr_b16 %0, %1"                                 \
                 : "=v"(arr[_k].s[0]) : "v"((lds_p3)_a0));                   \
    asm volatile("ds_read_b64_tr_b16 %0, %1"                                 \
                 : "=v"(arr[_k].s[1]) : "v"((lds_p3)(_a0 + 8192)));          \
  }

#define MF4X(arr, NTB, PA0, PA1)                                             \
  _Pragma("unroll") for (int _k = 0; _k < 4; ++_k) {                         \
    acc[0][(NTB) + _k] = MFMA((PA0), arr[_k].v, acc[0][(NTB) + _k]);         \
    acc[1][(NTB) + _k] = MFMA((PA1), arr[_k].v, acc[1][(NTB) + _k]);         \
  }

  // prologue: tile 0 staged and drained (syncthreads emits vmcnt(0))
  STAGE(0);
  __syncthreads();

  for (int t = 0; t < ntiles; ++t) {
    const char* buf = ring + ((t & 1) << 16);

    // ================= QK: S^T partial over this wave's 256-d slice =========
#pragma unroll
    for (int vt = 0; vt < 2; ++vt) {
      const char* bp = buf + (((4 * vt + (c >> 2)) * 64 + 16 * ds + (g >> 1)) * 128 +
                              (c & 3) * 32 + (g & 1) * 16);
      f4v st0 = fzero, st1 = fzero;
#pragma unroll
      for (int kt = 0; kt < 8; ++kt) {
        s8v ek = *(const s8v*)(bp + kt * 256);
        st0 = MFMA(ek, qf[0][kt], st0);
        st1 = MFMA(ek, qf[1][kt], st1);
      }
      int qb = ((mh * 4 + vt * 2) * 4 + ds) * 64 + l;
      uint2 pk;
      pk.x = pk_rn(st0[0], st0[1]); pk.y = pk_rn(st0[2], st0[3]);
      Sred[qb] = pk;
      pk.x = pk_rn(st1[0], st1[1]); pk.y = pk_rn(st1[2], st1[3]);
      Sred[qb + 256] = pk;             // mt=1 -> quadrant q+1
    }
    __syncthreads();                   // B1: Sred visible; drains prior STAGE DMA
                                       // (issued a full PV-phase ago -> hidden)

    // ================= softmax: wave (ds,mh) owns quadrant =================
    {
      int qq = mh * 4 + ds;
      f4v ss = fzero;
#pragma unroll
      for (int ww = 0; ww < 4; ++ww) {
        uint2 u = Sred[(qq * 4 + ww) * 64 + l];
        ss[0] += bfu_lo(u.x); ss[1] += bfu_hi(u.x);
        ss[2] += bfu_lo(u.y); ss[3] += bfu_hi(u.y);
      }
      float p0 = EXP2(ss[0]), p1 = EXP2(ss[1]);
      float p2 = EXP2(ss[2]), p3 = EXP2(ss[3]);
      int pb = mh * 2048 + (16 * (ds & 1) + c) * 64 + (16 * (ds >> 1) + 4 * g) * 2;
      uint2 pw; pw.x = pk_rn(p0, p1); pw.y = pk_rn(p2, p3);
      *(uint2*)(Plds + pb) = pw;
      lcur += (p0 + p1) + (p2 + p3);   // row-sum shfl deferred to epilogue
    }
    __syncthreads();                   // B2: P visible (no DMA in flight here)

    // stage next tile: in flight across PV + next QK, drained at next B1
    if (t + 1 < ntiles) STAGE(t + 1);

    // ================= PV: rolling 4-nt pipeline ============================
    {
      int pab = mh * 2048 + c * 64 + g * 16;
      s8v pa0 = *(const s8v*)(Plds + pab);
      s8v pa1 = *(const s8v*)(Plds + pab + 1024);
      const char* ab = buf + ((2 * g) * 64 + 16 * ds) * 128 + c * 2;
      union uev { s4v s[2]; s8v v; };
      uev ev0[4], ev1[4];
      TR4X(ev0, 0, ab);                // batch 0 (only exposed latency)
      LGKM0_SB();
      TR4X(ev1, 4, ab);                // batch 1 in flight under batch-0 MFMAs
      MF4X(ev0, 0, pa0, pa1);
      LGKM0_SB();
      TR4X(ev0, 8, ab);                // batch 2 under batch-1 MFMAs
      MF4X(ev1, 4, pa0, pa1);
      LGKM0_SB();
      TR4X(ev1, 12, ab);               // batch 3 under batch-2 MFMAs
      MF4X(ev0, 8, pa0, pa1);
      LGKM0_SB();
      MF4X(ev1, 12, pa0, pa1);
    }
  }
#undef STAGE
#undef TR4X
#undef MF4X

  // ---- finalize: deferred row-sum reduction, then normalize+write
  {
    float lp = lcur;
    lp += __shfl_xor(lp, 16);
    lp += __shfl_xor(lp, 32);
    __syncthreads();
    if (g == 0) lred[mh * 4 + ds][c] = lp;
  }
  __syncthreads();

  if (NSPLIT == 1) {
#pragma unroll
    for (int mt = 0; mt < 2; ++mt) {
      float inv[4];
#pragma unroll
      for (int r = 0; r < 4; ++r)
        inv[r] = 1.f / (lred[mh * 4 + mt][4 * g + r] + lred[mh * 4 + 2 + mt][4 * g + r]);
#pragma unroll
      for (int nt = 0; nt < 16; ++nt)
#pragma unroll
        for (int r = 0; r < 4; ++r) {
          size_t o = (size_t)(row0 + mh * 32 + 16 * mt + 4 * g + r) * D_DIM +
                     ds * 256 + 16 * nt + c;
          out[o] = acc[mt][nt][r] * inv[r] + qg[o];
        }
    }
  } else {
    u16* pc = pctx + (size_t)sp * NROWSZ * D_DIM;
#pragma unroll
    for (int mt = 0; mt < 2; ++mt)
#pragma unroll
      for (int nt = 0; nt < 16; ++nt)
#pragma unroll
        for (int r = 0; r < 4; ++r)
          pc[(size_t)(row0 + mh * 32 + 16 * mt + 4 * g + r) * D_DIM +
             ds * 256 + 16 * nt + c] = f2bf(acc[mt][nt][r]);
    if (ds < 2 && g == 0)
      pstat[(size_t)sp * NROWSZ + row0 + mh * 32 + 16 * ds + c] =
          lred[mh * 4 + ds][c] + lred[mh * 4 + 2 + ds][c];
  }
}

// ---------------------------------------------------------------------------
// Combine NSPLIT=4 partials: out = (sum ctx_sp) / (sum l_sp) + q
// ---------------------------------------------------------------------------
__global__ __launch_bounds__(256) void combine2_kernel(const float* __restrict__ qg,
                                                       const u16* __restrict__ pctx,
                                                       const float* __restrict__ pstat,
                                                       float* __restrict__ out) {
  const int r = blockIdx.x;
  const int t = threadIdx.x;
  float L = pstat[r] + pstat[NROWSZ + r] + pstat[2 * NROWSZ + r] + pstat[3 * NROWSZ + r];
  float inv = 1.f / L;
  size_t o = (size_t)r * D_DIM + t * 4;
  float sx = 0.f, sy = 0.f, sz = 0.f, sw = 0.f;
#pragma unroll
  for (int sp = 0; sp < 4; ++sp) {
    ushort4 u = *(const ushort4*)(pctx + (size_t)sp * NROWSZ * D_DIM + o);
    sx += bf2f(u.x); sy += bf2f(u.y); sz += bf2f(u.z); sw += bf2f(u.w);
  }
  float4 qv = *(const float4*)(qg + o);
  float4 res;
  res.x = sx * inv + qv.x;
  res.y = sy * inv + qv.y;
  res.z = sz * inv + qv.z;
  res.w = sw * inv + qv.w;
  *(float4*)(out + o) = res;
}

// ---------------------------------------------------------------------------
// Naive correctness fallback (tiny ws): one q-row per block.
// ---------------------------------------------------------------------------
__global__ __launch_bounds__(256) void naive_kernel(const float* __restrict__ qg,
                                                    const float* __restrict__ emb,
                                                    float* __restrict__ out) {
  __shared__ float s[VOCABSZ];
  __shared__ float qrow[D_DIM];
  __shared__ float lsh[4];
  const int r = blockIdx.x;
  const int t = threadIdx.x;
  for (int i = t; i < D_DIM; i += 256) qrow[i] = qg[(size_t)r * D_DIM + i];
  __syncthreads();
  float lpart = 0.f;
  for (int v = t; v < VOCABSZ; v += 256) {
    float dot = 0.f;
    for (int d = 0; d < D_DIM; d += 4) {
      float4 e = *(const float4*)(emb + (size_t)v * D_DIM + d);
      dot += qrow[d] * e.x + qrow[d + 1] * e.y + qrow[d + 2] * e.z + qrow[d + 3] * e.w;
    }
    float p = exp2f(dot * LOG2E);
    s[v] = p;
    lpart += p;
  }
  for (int o = 32; o; o >>= 1) lpart += __shfl_xor(lpart, o);
  if ((t & 63) == 0) lsh[t >> 6] = lpart;
  __syncthreads();
  float inv = 1.f / (lsh[0] + lsh[1] + lsh[2] + lsh[3]);
  float ax = 0.f, ay = 0.f, az = 0.f, aw = 0.f;
  for (int v = 0; v < VOCABSZ; ++v) {
    float p = s[v];
    float4 e = *(const float4*)(emb + (size_t)v * D_DIM + t * 4);
    ax += p * e.x; ay += p * e.y; az += p * e.z; aw += p * e.w;
  }
  size_t o = (size_t)r * D_DIM + t * 4;
  float4 qv = *(const float4*)(qg + o);
  float4 res;
  res.x = ax * inv + qv.x;
  res.y = ay * inv + qv.y;
  res.z = az * inv + qv.z;
  res.w = aw * inv + qv.w;
  *(float4*)(out + o) = res;
}

extern "C" void kernel_launch(void* const* d_in, const int* in_sizes, int n_in,
                              void* d_out, int out_size, void* d_ws, size_t ws_size,
                              hipStream_t stream) {
  const float* q = (const float*)d_in[0];
  const float* emb = (const float*)d_in[1];
  float* out = (float*)d_out;
  char* ws = (char*)d_ws;

  const size_t ETT_BYTES = 65536000ull;                      // 1000 tiles x 64 KB
  const size_t PCTX_BYTES = 4ull * NROWSZ * D_DIM * 2;       // 33,554,432
  const size_t PSTAT_BYTES = 4ull * NROWSZ * 4;              // 65,536

  if (ws_size >= ETT_BYTES + PCTX_BYTES + PSTAT_BYTES) {     // 99,155,968
    char* ETt = ws;
    u16* pctx = (u16*)(ws + ETT_BYTES);
    float* pstat = (float*)(ws + ETT_BYTES + PCTX_BYTES);
    cvt3_kernel<<<VOCABSZ / 32, 256, 0, stream>>>(emb, ETt);
    flash13_kernel<4><<<256, 512, 0, stream>>>(q, ETt, out, pctx, pstat);
    combine2_kernel<<<NROWSZ, 256, 0, stream>>>(q, pctx, pstat, out);
  } else if (ws_size >= ETT_BYTES) {
    char* ETt = ws;
    cvt3_kernel<<<VOCABSZ / 32, 256, 0, stream>>>(emb, ETt);
    flash13_kernel<1><<<NROWSZ / MBLK, 512, 0, stream>>>(q, ETt, out, nullptr, nullptr);
  } else {
    naive_kernel<<<NROWSZ, 256, 0, stream>>>(q, emb, out);
  }
}